// Round 3
// baseline (1140.512 us; speedup 1.0000x reference)
//
#include <hip/hip_runtime.h>
#include <math.h>

#define NN 50000
#define EE 800000
#define D 128
#define EDIM 32
#define LL 3
#define NT 2
#define ET 3
#define NB 196       // ceil(NN/256)
#define NPAD 50080   // >= align64(c0) + c1 for any split; multiple of 32
#define NTILE 1565   // NPAD/32

// ---------------- node-type permutation ----------------
__global__ __launch_bounds__(256) void k_tcount(const int* __restrict__ nt, int* __restrict__ meta) {
    __shared__ int s[256];
    int d = blockIdx.x * 256 + threadIdx.x;
    s[threadIdx.x] = (d < NN && nt[d] == 0) ? 1 : 0;
    __syncthreads();
    for (int st = 128; st; st >>= 1) {
        if (threadIdx.x < st) s[threadIdx.x] += s[threadIdx.x + st];
        __syncthreads();
    }
    if (threadIdx.x == 0) atomicAdd(&meta[0], s[0]);
}

__global__ void k_tbase(int* meta) {
    if (threadIdx.x == 0 && blockIdx.x == 0) meta[3] = (meta[0] + 63) & ~63;
}

__global__ __launch_bounds__(256) void k_passign(const int* __restrict__ nt, int* __restrict__ meta,
                                                 int* __restrict__ pos, int* __restrict__ inv) {
    int d = blockIdx.x * 256 + threadIdx.x;
    if (d >= NN) return;
    int t = nt[d];
    int base = t ? meta[3] : 0;
    int p = base + atomicAdd(&meta[1 + t], 1);
    pos[d] = p;
    inv[p] = d;
}

__global__ __launch_bounds__(256) void k_permx(const float* __restrict__ x, const int* __restrict__ pos,
                                               float* __restrict__ h0) {
    int flat = blockIdx.x * 256 + threadIdx.x;
    if (flat >= NN * 32) return;
    int d = flat >> 5, f4 = flat & 31;
    int p = pos[d];
    ((float4*)h0)[(size_t)p * 32 + f4] = ((const float4*)x)[(size_t)d * 32 + f4];
}

// ---------------- histogram of dst ----------------
__global__ __launch_bounds__(256) void k_hist(const int* __restrict__ dst, int* __restrict__ deg) {
    int e = blockIdx.x * 256 + threadIdx.x;
    if (e < EE) atomicAdd(&deg[dst[e]], 1);
}

// ---------------- 2-level exclusive scan ----------------
__global__ __launch_bounds__(256) void k_scan_bsum(const int* __restrict__ deg, int* __restrict__ bsum) {
    __shared__ int s[256];
    int t = threadIdx.x;
    int d = blockIdx.x * 256 + t;
    s[t] = (d < NN) ? deg[d] : 0;
    __syncthreads();
    for (int st = 128; st > 0; st >>= 1) {
        if (t < st) s[t] += s[t + st];
        __syncthreads();
    }
    if (t == 0) bsum[blockIdx.x] = s[0];
}

__global__ __launch_bounds__(256) void k_scan_boff(const int* __restrict__ bsum, int* __restrict__ boff) {
    __shared__ int s[256];
    int t = threadIdx.x;
    s[t] = (t < NB) ? bsum[t] : 0;
    __syncthreads();
    for (int st = 1; st < 256; st <<= 1) {
        int add = (t >= st) ? s[t - st] : 0;
        __syncthreads();
        s[t] += add;
        __syncthreads();
    }
    if (t < NB) boff[t] = (t == 0) ? 0 : s[t - 1];
}

__global__ __launch_bounds__(256) void k_scan_offs(const int* __restrict__ deg, const int* __restrict__ boff,
                                                   int* __restrict__ offs, int* __restrict__ cur) {
    __shared__ int s[256];
    int t = threadIdx.x;
    int d = blockIdx.x * 256 + t;
    int v = (d < NN) ? deg[d] : 0;
    s[t] = v;
    __syncthreads();
    for (int st = 1; st < 256; st <<= 1) {
        int add = (t >= st) ? s[t - st] : 0;
        __syncthreads();
        s[t] += add;
        __syncthreads();
    }
    if (d < NN) {
        int excl = s[t] - v + boff[blockIdx.x];
        offs[d] = excl;
        cur[d]  = excl;
    }
}

// ------------- per-edge scalars (all 3 layers) packed + scattered into dst-sorted order -------------
__global__ __launch_bounds__(256) void k_edge(const float* __restrict__ edge_attr,
                                              const float* __restrict__ edge_W,
                                              const float* __restrict__ edge_b,
                                              const float* __restrict__ emb,
                                              const int* __restrict__ ei,
                                              const int* __restrict__ etype,
                                              const int* __restrict__ pos,
                                              int* __restrict__ cur,
                                              float4* __restrict__ esort) {
    __shared__ float eWl[LL * ET * 2 * EDIM];   // 576 floats
    __shared__ float ebd[LL * ET * 2];          // emb·eW + eb, 18 floats
    int t0 = threadIdx.x;
    for (int i = t0; i < LL * ET * 2 * EDIM; i += 256) eWl[i] = edge_W[i];
    __syncthreads();
    if (t0 < LL * ET * 2) {
        int l = t0 / (ET * 2);
        int rem = t0 % (ET * 2);
        int tt = rem / 2;
        float sum = edge_b[t0];
        const float* em = emb + (l * ET + tt) * EDIM;
        const float* w  = eWl + t0 * EDIM;
        for (int c = 0; c < EDIM; c++) sum += em[c] * w[c];
        ebd[t0] = sum;
    }
    __syncthreads();
    int e = blockIdx.x * 256 + t0;
    if (e >= EE) return;

    float a[EDIM];
    const float4* ap = (const float4*)(edge_attr + (size_t)e * EDIM);
#pragma unroll
    for (int i = 0; i < EDIM / 4; i++) {
        float4 v = ap[i];
        a[4 * i + 0] = v.x; a[4 * i + 1] = v.y; a[4 * i + 2] = v.z; a[4 * i + 3] = v.w;
    }
    int tt = etype[e];
    float dir  = a[EDIM - 2];
    float pump = a[EDIM - 1];
    float sign = dir * 2.f - 1.f;
    float speed = pump * (dir > 0.f ? dir : 1.f);
    int src = ei[e];
    int dst = ei[EE + e];
    int sp = pos[src];
    int p = atomicAdd(&cur[dst], 1);
    float Av[LL], Bv[LL];
#pragma unroll
    for (int l = 0; l < LL; l++) {
        const float* w0 = eWl + ((l * ET + tt) * 2 + 0) * EDIM;
        const float* w1 = w0 + EDIM;
        float r0 = ebd[(l * ET + tt) * 2 + 0];
        float r1 = ebd[(l * ET + tt) * 2 + 1];
#pragma unroll
        for (int c = 0; c < EDIM; c++) { r0 += a[c] * w0[c]; r1 += a[c] * w1[c]; }
        float gain = fmaxf(r0, 0.f) + log1pf(expf(-fabsf(r0)));   // stable softplus
        float bias = 0.f;
        if (tt == 1) { gain *= speed; bias = r1 * speed; }        // PUMP == 1
        Av[l] = sign * gain;
        Bv[l] = sign * bias;
    }
    float4 e0 = make_float4(__int_as_float(sp), Av[0], Av[1], Av[2]);
    float4 e1 = make_float4(Bv[0], Bv[1], Bv[2], 0.f);
    esort[(size_t)p * 2 + 0] = e0;
    esort[(size_t)p * 2 + 1] = e1;
}

// ------------- gather: aggr[pos[d]] = sum A*h[spos] - sA*h[pos[d]] + sB -------------
// 2 nodes / block; per node 4 edge-workers x 32 float4-lanes
__global__ __launch_bounds__(256) void k_gather(const float* __restrict__ h,
                                                const int* __restrict__ offs,
                                                const int* __restrict__ deg,
                                                const int* __restrict__ pos,
                                                const float4* __restrict__ esort,
                                                int layer,
                                                float* __restrict__ aggr) {
    __shared__ float4 rbuf[2][32];
    __shared__ float  rsum[2][2];
    int local = threadIdx.x;
    int nb = local >> 7;                    // node within block
    int node = blockIdx.x * 2 + nb;
    int t = local & 127;
    int w = t >> 5;                         // worker 0..3
    int f4 = t & 31;                        // feature-quad lane
    int start = offs[node];
    int n = deg[node];
    int p = pos[node];

    float4 acc = make_float4(0.f, 0.f, 0.f, 0.f);
    float sA = 0.f, sB = 0.f;
    for (int k = w; k < n; k += 4) {
        size_t idx = (size_t)(start + k) * 2;
        float4 e0 = esort[idx];
        float4 e1 = esort[idx + 1];
        int sp = __float_as_int(e0.x);
        float A = (layer == 0) ? e0.y : ((layer == 1) ? e0.z : e0.w);
        float B = (layer == 0) ? e1.x : ((layer == 1) ? e1.y : e1.z);
        float4 hv = *(const float4*)&h[(size_t)sp * D + 4 * f4];
        acc.x += A * hv.x; acc.y += A * hv.y; acc.z += A * hv.z; acc.w += A * hv.w;
        sA += A; sB += B;
    }
    // combine worker pairs within wave (lanes l and l^32)
    acc.x += __shfl_xor(acc.x, 32); acc.y += __shfl_xor(acc.y, 32);
    acc.z += __shfl_xor(acc.z, 32); acc.w += __shfl_xor(acc.w, 32);
    sA += __shfl_xor(sA, 32); sB += __shfl_xor(sB, 32);
    // cross-wave combine via LDS: upper wave of each node writes, lower reads
    if (((local >> 6) & 1) == 1 && (t & 63) < 32) {
        rbuf[nb][f4] = acc;
        if (f4 == 0) { rsum[nb][0] = sA; rsum[nb][1] = sB; }
    }
    __syncthreads();
    if (((local >> 6) & 1) == 0 && (t & 63) < 32) {
        float4 o = rbuf[nb][f4];
        float sAt = sA + rsum[nb][0];
        float sBt = sB + rsum[nb][1];
        float4 hd = *(const float4*)&h[(size_t)p * D + 4 * f4];
        float4 r;
        r.x = acc.x + o.x - sAt * hd.x + sBt;
        r.y = acc.y + o.y - sAt * hd.y + sBt;
        r.z = acc.z + o.z - sAt * hd.z + sBt;
        r.w = acc.w + o.w - sAt * hd.w + sBt;
        *(float4*)&aggr[(size_t)p * D + 4 * f4] = r;
    }
}

// ------------- node transform + ReLU + LayerNorm + residual (uniform type per tile) -------------
__global__ __launch_bounds__(256) void k_node(const float* __restrict__ aggr,
                                              const float* __restrict__ hprev,
                                              const float* __restrict__ Wg,   // node_W + l*NT*D*D
                                              const float* __restrict__ bg,   // node_b + l*NT*D
                                              const float* __restrict__ lng,
                                              const float* __restrict__ lnb,
                                              const int* __restrict__ meta,
                                              float* __restrict__ hnext) {
    __shared__ float As[32 * 132];   // [m][k], stride 132
    __shared__ float Ws[128 * 68];   // [o][k-half], stride 68
    int tid = threadIdx.x;
    int m0 = blockIdx.x * 32;
    int tt = (m0 >= meta[3]) ? 1 : 0;
    const float* W = Wg + (size_t)tt * D * D;

    // stage A tile (coalesced float4): 32 rows x 32 float4 = 1024 = 4 reps
#pragma unroll
    for (int rep = 0; rep < 4; rep++) {
        int flat = rep * 256 + tid;
        int r = flat >> 5, k4 = flat & 31;
        float4 v = *(const float4*)&aggr[(size_t)(m0 + r) * D + 4 * k4];
        *(float4*)&As[r * 132 + 4 * k4] = v;
    }

    int og = tid & 31, mg = tid >> 5;   // o = og + 32j, m = mg + 8i
    float acc[4][4];
#pragma unroll
    for (int i = 0; i < 4; i++)
#pragma unroll
        for (int j = 0; j < 4; j++) acc[i][j] = 0.f;

    for (int half = 0; half < 2; half++) {
        __syncthreads();
        // stage W half: 128 rows x 16 float4 = 2048 = 8 reps  (was 32: LDS overrun bug)
#pragma unroll
        for (int rep = 0; rep < 8; rep++) {
            int flat = rep * 256 + tid;
            int r = flat >> 4, k4 = flat & 15;
            float4 v = *(const float4*)&W[(size_t)r * D + half * 64 + 4 * k4];
            *(float4*)&Ws[r * 68 + 4 * k4] = v;
        }
        __syncthreads();
#pragma unroll
        for (int kk = 0; kk < 64; kk += 4) {
            float4 a[4], wv[4];
#pragma unroll
            for (int i = 0; i < 4; i++) a[i] = *(const float4*)&As[(mg + 8 * i) * 132 + half * 64 + kk];
#pragma unroll
            for (int j = 0; j < 4; j++) wv[j] = *(const float4*)&Ws[(og + 32 * j) * 68 + kk];
#pragma unroll
            for (int i = 0; i < 4; i++)
#pragma unroll
                for (int j = 0; j < 4; j++)
                    acc[i][j] += a[i].x * wv[j].x + a[i].y * wv[j].y + a[i].z * wv[j].z + a[i].w * wv[j].w;
        }
    }

    // epilogue: bias + relu + LN + residual
    float bj[4], gj[4], lj[4];
#pragma unroll
    for (int j = 0; j < 4; j++) {
        int o = og + 32 * j;
        bj[j] = bg[tt * D + o];
        gj[j] = lng[o];
        lj[j] = lnb[o];
    }
    float c[4][4];
#pragma unroll
    for (int i = 0; i < 4; i++)
#pragma unroll
        for (int j = 0; j < 4; j++) c[i][j] = fmaxf(acc[i][j] + bj[j], 0.f);

    float mu[4], rs[4];
#pragma unroll
    for (int i = 0; i < 4; i++) {
        float s = 0.f, s2 = 0.f;
#pragma unroll
        for (int j = 0; j < 4; j++) { s += c[i][j]; s2 += c[i][j] * c[i][j]; }
#pragma unroll
        for (int m = 1; m < 32; m <<= 1) { s += __shfl_xor(s, m); s2 += __shfl_xor(s2, m); }
        float mm = s * (1.f / 128.f);
        float vv = s2 * (1.f / 128.f) - mm * mm;
        mu[i] = mm;
        rs[i] = rsqrtf(vv + 1e-5f);
    }
#pragma unroll
    for (int i = 0; i < 4; i++) {
        int row = m0 + mg + 8 * i;
#pragma unroll
        for (int j = 0; j < 4; j++) {
            int o = og + 32 * j;
            float v = (c[i][j] - mu[i]) * rs[i] * gj[j] + lj[j] + hprev[(size_t)row * D + o];
            hnext[(size_t)row * D + o] = v;
        }
    }
}

// ------------- final FC with un-permute -------------
__global__ __launch_bounds__(256) void k_fc(const float* __restrict__ hin,
                                            const float* __restrict__ W,
                                            const float* __restrict__ bias,
                                            const int* __restrict__ inv,
                                            float* __restrict__ out) {
    __shared__ float As[32 * 132];
    __shared__ float Ws[128 * 68];
    int tid = threadIdx.x;
    int m0 = blockIdx.x * 32;
#pragma unroll
    for (int rep = 0; rep < 4; rep++) {
        int flat = rep * 256 + tid;
        int r = flat >> 5, k4 = flat & 31;
        float4 v = *(const float4*)&hin[(size_t)(m0 + r) * D + 4 * k4];
        *(float4*)&As[r * 132 + 4 * k4] = v;
    }
    int og = tid & 31, mg = tid >> 5;
    float acc[4][4];
#pragma unroll
    for (int i = 0; i < 4; i++)
#pragma unroll
        for (int j = 0; j < 4; j++) acc[i][j] = 0.f;

    for (int half = 0; half < 2; half++) {
        __syncthreads();
        // 128 rows x 16 float4 = 2048 = 8 reps (was 32: LDS overrun bug)
#pragma unroll
        for (int rep = 0; rep < 8; rep++) {
            int flat = rep * 256 + tid;
            int r = flat >> 4, k4 = flat & 15;
            float4 v = *(const float4*)&W[(size_t)r * D + half * 64 + 4 * k4];
            *(float4*)&Ws[r * 68 + 4 * k4] = v;
        }
        __syncthreads();
#pragma unroll
        for (int kk = 0; kk < 64; kk += 4) {
            float4 a[4], wv[4];
#pragma unroll
            for (int i = 0; i < 4; i++) a[i] = *(const float4*)&As[(mg + 8 * i) * 132 + half * 64 + kk];
#pragma unroll
            for (int j = 0; j < 4; j++) wv[j] = *(const float4*)&Ws[(og + 32 * j) * 68 + kk];
#pragma unroll
            for (int i = 0; i < 4; i++)
#pragma unroll
                for (int j = 0; j < 4; j++)
                    acc[i][j] += a[i].x * wv[j].x + a[i].y * wv[j].y + a[i].z * wv[j].z + a[i].w * wv[j].w;
        }
    }
    float bj[4];
#pragma unroll
    for (int j = 0; j < 4; j++) bj[j] = bias[og + 32 * j];
#pragma unroll
    for (int i = 0; i < 4; i++) {
        int row = m0 + mg + 8 * i;
        int orig = inv[row];
        if (orig >= 0) {
#pragma unroll
            for (int j = 0; j < 4; j++)
                out[(size_t)orig * D + og + 32 * j] = acc[i][j] + bj[j];
        }
    }
}

extern "C" void kernel_launch(void* const* d_in, const int* in_sizes, int n_in,
                              void* d_out, int out_size, void* d_ws, size_t ws_size,
                              hipStream_t stream) {
    const float* x         = (const float*)d_in[0];
    const float* edge_attr = (const float*)d_in[1];
    const float* node_W    = (const float*)d_in[2];
    const float* node_b    = (const float*)d_in[3];
    const float* edge_W    = (const float*)d_in[4];
    const float* edge_b    = (const float*)d_in[5];
    const float* emb       = (const float*)d_in[6];
    const float* ln_g      = (const float*)d_in[7];
    const float* ln_b      = (const float*)d_in[8];
    const float* fc_W      = (const float*)d_in[9];
    const float* fc_b      = (const float*)d_in[10];
    const int*   edge_index = (const int*)d_in[11];
    const int*   node_type  = (const int*)d_in[12];
    const int*   edge_type  = (const int*)d_in[13];
    float* out = (float*)d_out;

    char* w = (char*)d_ws;
    auto alloc = [&](size_t bytes) {
        void* p = (void*)w;
        w += (bytes + 255) & ~(size_t)255;
        return p;
    };
    float*  P     = (float*)alloc((size_t)NPAD * D * 4);   // permuted x / layer buffers
    float*  Q     = (float*)alloc((size_t)NPAD * D * 4);
    float*  G     = (float*)alloc((size_t)NPAD * D * 4);   // aggr
    float4* esort = (float4*)alloc((size_t)EE * 32);
    int*    pos   = (int*)alloc((size_t)NN * 4);
    int*    inv   = (int*)alloc((size_t)NPAD * 4);
    int*    deg   = (int*)alloc((size_t)NN * 4);
    int*    offs  = (int*)alloc((size_t)NN * 4);
    int*    cur   = (int*)alloc((size_t)NN * 4);
    int*    bsum  = (int*)alloc(256 * 4);
    int*    boff  = (int*)alloc(256 * 4);
    int*    meta  = (int*)alloc(8 * 4);

    hipMemsetAsync(deg, 0, (size_t)NN * 4, stream);
    hipMemsetAsync(meta, 0, 8 * 4, stream);
    hipMemsetAsync(inv, 0xFF, (size_t)NPAD * 4, stream);   // -1 = "gap row", k_fc skips

    k_tcount<<<NB, 256, 0, stream>>>(node_type, meta);
    k_tbase<<<1, 64, 0, stream>>>(meta);
    k_passign<<<NB, 256, 0, stream>>>(node_type, meta, pos, inv);
    k_permx<<<(NN * 32 + 255) / 256, 256, 0, stream>>>(x, pos, P);

    k_hist<<<(EE + 255) / 256, 256, 0, stream>>>(edge_index + EE, deg);
    k_scan_bsum<<<NB, 256, 0, stream>>>(deg, bsum);
    k_scan_boff<<<1, 256, 0, stream>>>(bsum, boff);
    k_scan_offs<<<NB, 256, 0, stream>>>(deg, boff, offs, cur);
    k_edge<<<(EE + 255) / 256, 256, 0, stream>>>(edge_attr, edge_W, edge_b, emb,
                                                 edge_index, edge_type, pos, cur, esort);

    // layer rotation: P -> Q -> P -> Q   (in, out per layer)
    const float* hin = P;
    float* outs[LL] = {Q, P, Q};
    for (int l = 0; l < LL; l++) {
        k_gather<<<NN / 2, 256, 0, stream>>>(hin, offs, deg, pos, esort, l, G);
        k_node<<<NTILE, 256, 0, stream>>>(G, hin,
                                          node_W + (size_t)l * NT * D * D,
                                          node_b + (size_t)l * NT * D,
                                          ln_g + (size_t)l * D,
                                          ln_b + (size_t)l * D,
                                          meta, outs[l]);
        hin = outs[l];
    }
    k_fc<<<NTILE, 256, 0, stream>>>(hin, fc_W, fc_b, inv, out);
}

// Round 4
// 750.640 us; speedup vs baseline: 1.5194x; 1.5194x over previous
//
#include <hip/hip_runtime.h>
#include <math.h>

#define NN 50000
#define EE 800000
#define D 128
#define EDIM 32
#define LL 3
#define NT 2
#define ET 3
#define NB 196       // ceil(NN/256)
#define NPAD 50080   // >= align64(c0) + c1 for any split; multiple of 32
#define NTILE 1565   // NPAD/32

// ---------------- node-type permutation (deterministic, scan-based) ----------------
// packed counts: low 16 = type0, high 16 = type1 (totals <= 50000 < 65536)
__global__ __launch_bounds__(256) void k_pcount(const int* __restrict__ nt, int* __restrict__ pc) {
    __shared__ int s[256];
    int d = blockIdx.x * 256 + threadIdx.x;
    int ind = 0;
    if (d < NN) ind = (nt[d] == 0) ? 1 : 0x10000;
    s[threadIdx.x] = ind;
    __syncthreads();
    for (int st = 128; st; st >>= 1) {
        if (threadIdx.x < st) s[threadIdx.x] += s[threadIdx.x + st];
        __syncthreads();
    }
    if (threadIdx.x == 0) pc[blockIdx.x] = s[0];
}

__global__ __launch_bounds__(256) void k_pscan(const int* __restrict__ pc, int* __restrict__ po,
                                               int* __restrict__ meta) {
    __shared__ int s[256];
    int t = threadIdx.x;
    int v = (t < NB) ? pc[t] : 0;
    s[t] = v;
    __syncthreads();
    for (int st = 1; st < 256; st <<= 1) {
        int add = (t >= st) ? s[t - st] : 0;
        __syncthreads();
        s[t] += add;
        __syncthreads();
    }
    if (t < NB) po[t] = s[t] - v;                     // exclusive packed block offsets
    if (t == 0) {
        int tot = s[255];
        meta[3] = ((tot & 0xffff) + 63) & ~63;        // aligned base for type-1 region
    }
}

__global__ __launch_bounds__(256) void k_passign(const int* __restrict__ nt, const int* __restrict__ po,
                                                 const int* __restrict__ meta,
                                                 int* __restrict__ pos, int* __restrict__ inv) {
    __shared__ int s[256];
    int t = threadIdx.x;
    int d = blockIdx.x * 256 + t;
    int ty = (d < NN) ? nt[d] : -1;
    int ind = (ty == 0) ? 1 : ((ty == 1) ? 0x10000 : 0);
    s[t] = ind;
    __syncthreads();
    for (int st = 1; st < 256; st <<= 1) {
        int add = (t >= st) ? s[t - st] : 0;
        __syncthreads();
        s[t] += add;
        __syncthreads();
    }
    if (d >= NN) return;
    int excl = s[t] - ind;
    int pop = po[blockIdx.x];
    int p;
    if (ty == 0) p = (pop & 0xffff) + (excl & 0xffff);
    else         p = meta[3] + (pop >> 16) + (excl >> 16);
    pos[d] = p;
    inv[p] = d;
}

__global__ __launch_bounds__(256) void k_permx(const float* __restrict__ x, const int* __restrict__ pos,
                                               float* __restrict__ h0) {
    int flat = blockIdx.x * 256 + threadIdx.x;
    if (flat >= NN * 32) return;
    int d = flat >> 5, f4 = flat & 31;
    int p = pos[d];
    ((float4*)h0)[(size_t)p * 32 + f4] = ((const float4*)x)[(size_t)d * 32 + f4];
}

// ---------------- histogram of dst ----------------
__global__ __launch_bounds__(256) void k_hist(const int* __restrict__ dst, int* __restrict__ deg) {
    int e = blockIdx.x * 256 + threadIdx.x;
    if (e < EE) atomicAdd(&deg[dst[e]], 1);
}

// ---------------- 2-level exclusive scan ----------------
__global__ __launch_bounds__(256) void k_scan_bsum(const int* __restrict__ deg, int* __restrict__ bsum) {
    __shared__ int s[256];
    int t = threadIdx.x;
    int d = blockIdx.x * 256 + t;
    s[t] = (d < NN) ? deg[d] : 0;
    __syncthreads();
    for (int st = 128; st > 0; st >>= 1) {
        if (t < st) s[t] += s[t + st];
        __syncthreads();
    }
    if (t == 0) bsum[blockIdx.x] = s[0];
}

__global__ __launch_bounds__(256) void k_scan_boff(const int* __restrict__ bsum, int* __restrict__ boff) {
    __shared__ int s[256];
    int t = threadIdx.x;
    s[t] = (t < NB) ? bsum[t] : 0;
    __syncthreads();
    for (int st = 1; st < 256; st <<= 1) {
        int add = (t >= st) ? s[t - st] : 0;
        __syncthreads();
        s[t] += add;
        __syncthreads();
    }
    if (t < NB) boff[t] = (t == 0) ? 0 : s[t - 1];
}

__global__ __launch_bounds__(256) void k_scan_offs(const int* __restrict__ deg, const int* __restrict__ boff,
                                                   int* __restrict__ offs, int* __restrict__ cur) {
    __shared__ int s[256];
    int t = threadIdx.x;
    int d = blockIdx.x * 256 + t;
    int v = (d < NN) ? deg[d] : 0;
    s[t] = v;
    __syncthreads();
    for (int st = 1; st < 256; st <<= 1) {
        int add = (t >= st) ? s[t - st] : 0;
        __syncthreads();
        s[t] += add;
        __syncthreads();
    }
    if (d < NN) {
        int excl = s[t] - v + boff[blockIdx.x];
        offs[d] = excl;
        cur[d]  = excl;
    }
}

// ------------- per-edge scalars (all 3 layers) packed + scattered into dst-sorted order -------------
__global__ __launch_bounds__(256) void k_edge(const float* __restrict__ edge_attr,
                                              const float* __restrict__ edge_W,
                                              const float* __restrict__ edge_b,
                                              const float* __restrict__ emb,
                                              const int* __restrict__ ei,
                                              const int* __restrict__ etype,
                                              const int* __restrict__ pos,
                                              int* __restrict__ cur,
                                              float4* __restrict__ esort) {
    __shared__ float eWl[LL * ET * 2 * EDIM];   // 576 floats
    __shared__ float ebd[LL * ET * 2];          // emb·eW + eb, 18 floats
    int t0 = threadIdx.x;
    for (int i = t0; i < LL * ET * 2 * EDIM; i += 256) eWl[i] = edge_W[i];
    __syncthreads();
    if (t0 < LL * ET * 2) {
        int l = t0 / (ET * 2);
        int rem = t0 % (ET * 2);
        int tt = rem / 2;
        float sum = edge_b[t0];
        const float* em = emb + (l * ET + tt) * EDIM;
        const float* w  = eWl + t0 * EDIM;
        for (int c = 0; c < EDIM; c++) sum += em[c] * w[c];
        ebd[t0] = sum;
    }
    __syncthreads();
    int e = blockIdx.x * 256 + t0;
    if (e >= EE) return;

    float a[EDIM];
    const float4* ap = (const float4*)(edge_attr + (size_t)e * EDIM);
#pragma unroll
    for (int i = 0; i < EDIM / 4; i++) {
        float4 v = ap[i];
        a[4 * i + 0] = v.x; a[4 * i + 1] = v.y; a[4 * i + 2] = v.z; a[4 * i + 3] = v.w;
    }
    int tt = etype[e];
    float dir  = a[EDIM - 2];
    float pump = a[EDIM - 1];
    float sign = dir * 2.f - 1.f;
    float speed = pump * (dir > 0.f ? dir : 1.f);
    int src = ei[e];
    int dst = ei[EE + e];
    int sp = pos[src];
    int p = atomicAdd(&cur[dst], 1);
    float Av[LL], Bv[LL];
#pragma unroll
    for (int l = 0; l < LL; l++) {
        const float* w0 = eWl + ((l * ET + tt) * 2 + 0) * EDIM;
        const float* w1 = w0 + EDIM;
        float r0 = ebd[(l * ET + tt) * 2 + 0];
        float r1 = ebd[(l * ET + tt) * 2 + 1];
#pragma unroll
        for (int c = 0; c < EDIM; c++) { r0 += a[c] * w0[c]; r1 += a[c] * w1[c]; }
        float gain = fmaxf(r0, 0.f) + log1pf(expf(-fabsf(r0)));   // stable softplus
        float bias = 0.f;
        if (tt == 1) { gain *= speed; bias = r1 * speed; }        // PUMP == 1
        Av[l] = sign * gain;
        Bv[l] = sign * bias;
    }
    float4 e0 = make_float4(__int_as_float(sp), Av[0], Av[1], Av[2]);
    float4 e1 = make_float4(Bv[0], Bv[1], Bv[2], 0.f);
    esort[(size_t)p * 2 + 0] = e0;
    esort[(size_t)p * 2 + 1] = e1;
}

// ------------- gather: aggr[pos[d]] = sum A*h[spos] - sA*h[pos[d]] + sB -------------
// 2 nodes / block; per node 4 edge-workers x 32 float4-lanes
__global__ __launch_bounds__(256) void k_gather(const float* __restrict__ h,
                                                const int* __restrict__ offs,
                                                const int* __restrict__ deg,
                                                const int* __restrict__ pos,
                                                const float4* __restrict__ esort,
                                                int layer,
                                                float* __restrict__ aggr) {
    __shared__ float4 rbuf[2][32];
    __shared__ float  rsum[2][2];
    int local = threadIdx.x;
    int nb = local >> 7;                    // node within block
    int node = blockIdx.x * 2 + nb;
    int t = local & 127;
    int w = t >> 5;                         // worker 0..3
    int f4 = t & 31;                        // feature-quad lane
    int start = offs[node];
    int n = deg[node];
    int p = pos[node];

    float4 acc = make_float4(0.f, 0.f, 0.f, 0.f);
    float sA = 0.f, sB = 0.f;
    for (int k = w; k < n; k += 4) {
        size_t idx = (size_t)(start + k) * 2;
        float4 e0 = esort[idx];
        float4 e1 = esort[idx + 1];
        int sp = __float_as_int(e0.x);
        float A = (layer == 0) ? e0.y : ((layer == 1) ? e0.z : e0.w);
        float B = (layer == 0) ? e1.x : ((layer == 1) ? e1.y : e1.z);
        float4 hv = *(const float4*)&h[(size_t)sp * D + 4 * f4];
        acc.x += A * hv.x; acc.y += A * hv.y; acc.z += A * hv.z; acc.w += A * hv.w;
        sA += A; sB += B;
    }
    // combine worker pairs within wave (lanes l and l^32)
    acc.x += __shfl_xor(acc.x, 32); acc.y += __shfl_xor(acc.y, 32);
    acc.z += __shfl_xor(acc.z, 32); acc.w += __shfl_xor(acc.w, 32);
    sA += __shfl_xor(sA, 32); sB += __shfl_xor(sB, 32);
    // cross-wave combine via LDS: upper wave of each node writes, lower reads
    if (((local >> 6) & 1) == 1 && (t & 63) < 32) {
        rbuf[nb][f4] = acc;
        if (f4 == 0) { rsum[nb][0] = sA; rsum[nb][1] = sB; }
    }
    __syncthreads();
    if (((local >> 6) & 1) == 0 && (t & 63) < 32) {
        float4 o = rbuf[nb][f4];
        float sAt = sA + rsum[nb][0];
        float sBt = sB + rsum[nb][1];
        float4 hd = *(const float4*)&h[(size_t)p * D + 4 * f4];
        float4 r;
        r.x = acc.x + o.x - sAt * hd.x + sBt;
        r.y = acc.y + o.y - sAt * hd.y + sBt;
        r.z = acc.z + o.z - sAt * hd.z + sBt;
        r.w = acc.w + o.w - sAt * hd.w + sBt;
        *(float4*)&aggr[(size_t)p * D + 4 * f4] = r;
    }
}

// ------------- node transform + ReLU + LayerNorm + residual (uniform type per tile) -------------
__global__ __launch_bounds__(256) void k_node(const float* __restrict__ aggr,
                                              const float* __restrict__ hprev,
                                              const float* __restrict__ Wg,   // node_W + l*NT*D*D
                                              const float* __restrict__ bg,   // node_b + l*NT*D
                                              const float* __restrict__ lng,
                                              const float* __restrict__ lnb,
                                              const int* __restrict__ meta,
                                              float* __restrict__ hnext) {
    __shared__ float As[32 * 132];   // [m][k], stride 132
    __shared__ float Ws[128 * 68];   // [o][k-half], stride 68
    int tid = threadIdx.x;
    int m0 = blockIdx.x * 32;
    int tt = (m0 >= meta[3]) ? 1 : 0;
    const float* W = Wg + (size_t)tt * D * D;

    // stage A tile (coalesced float4): 32 rows x 32 float4 = 1024 = 4 reps
#pragma unroll
    for (int rep = 0; rep < 4; rep++) {
        int flat = rep * 256 + tid;
        int r = flat >> 5, k4 = flat & 31;
        float4 v = *(const float4*)&aggr[(size_t)(m0 + r) * D + 4 * k4];
        *(float4*)&As[r * 132 + 4 * k4] = v;
    }

    int og = tid & 31, mg = tid >> 5;   // o = og + 32j, m = mg + 8i
    float acc[4][4];
#pragma unroll
    for (int i = 0; i < 4; i++)
#pragma unroll
        for (int j = 0; j < 4; j++) acc[i][j] = 0.f;

    for (int half = 0; half < 2; half++) {
        __syncthreads();
        // stage W half: 128 rows x 16 float4 = 2048 = 8 reps
#pragma unroll
        for (int rep = 0; rep < 8; rep++) {
            int flat = rep * 256 + tid;
            int r = flat >> 4, k4 = flat & 15;
            float4 v = *(const float4*)&W[(size_t)r * D + half * 64 + 4 * k4];
            *(float4*)&Ws[r * 68 + 4 * k4] = v;
        }
        __syncthreads();
#pragma unroll
        for (int kk = 0; kk < 64; kk += 4) {
            float4 a[4], wv[4];
#pragma unroll
            for (int i = 0; i < 4; i++) a[i] = *(const float4*)&As[(mg + 8 * i) * 132 + half * 64 + kk];
#pragma unroll
            for (int j = 0; j < 4; j++) wv[j] = *(const float4*)&Ws[(og + 32 * j) * 68 + kk];
#pragma unroll
            for (int i = 0; i < 4; i++)
#pragma unroll
                for (int j = 0; j < 4; j++)
                    acc[i][j] += a[i].x * wv[j].x + a[i].y * wv[j].y + a[i].z * wv[j].z + a[i].w * wv[j].w;
        }
    }

    // epilogue: bias + relu + LN + residual
    float bj[4], gj[4], lj[4];
#pragma unroll
    for (int j = 0; j < 4; j++) {
        int o = og + 32 * j;
        bj[j] = bg[tt * D + o];
        gj[j] = lng[o];
        lj[j] = lnb[o];
    }
    float c[4][4];
#pragma unroll
    for (int i = 0; i < 4; i++)
#pragma unroll
        for (int j = 0; j < 4; j++) c[i][j] = fmaxf(acc[i][j] + bj[j], 0.f);

    float mu[4], rs[4];
#pragma unroll
    for (int i = 0; i < 4; i++) {
        float s = 0.f, s2 = 0.f;
#pragma unroll
        for (int j = 0; j < 4; j++) { s += c[i][j]; s2 += c[i][j] * c[i][j]; }
#pragma unroll
        for (int m = 1; m < 32; m <<= 1) { s += __shfl_xor(s, m); s2 += __shfl_xor(s2, m); }
        float mm = s * (1.f / 128.f);
        float vv = s2 * (1.f / 128.f) - mm * mm;
        mu[i] = mm;
        rs[i] = rsqrtf(vv + 1e-5f);
    }
#pragma unroll
    for (int i = 0; i < 4; i++) {
        int row = m0 + mg + 8 * i;
#pragma unroll
        for (int j = 0; j < 4; j++) {
            int o = og + 32 * j;
            float v = (c[i][j] - mu[i]) * rs[i] * gj[j] + lj[j] + hprev[(size_t)row * D + o];
            hnext[(size_t)row * D + o] = v;
        }
    }
}

// ------------- final FC with un-permute -------------
__global__ __launch_bounds__(256) void k_fc(const float* __restrict__ hin,
                                            const float* __restrict__ W,
                                            const float* __restrict__ bias,
                                            const int* __restrict__ inv,
                                            float* __restrict__ out) {
    __shared__ float As[32 * 132];
    __shared__ float Ws[128 * 68];
    int tid = threadIdx.x;
    int m0 = blockIdx.x * 32;
#pragma unroll
    for (int rep = 0; rep < 4; rep++) {
        int flat = rep * 256 + tid;
        int r = flat >> 5, k4 = flat & 31;
        float4 v = *(const float4*)&hin[(size_t)(m0 + r) * D + 4 * k4];
        *(float4*)&As[r * 132 + 4 * k4] = v;
    }
    int og = tid & 31, mg = tid >> 5;
    float acc[4][4];
#pragma unroll
    for (int i = 0; i < 4; i++)
#pragma unroll
        for (int j = 0; j < 4; j++) acc[i][j] = 0.f;

    for (int half = 0; half < 2; half++) {
        __syncthreads();
#pragma unroll
        for (int rep = 0; rep < 8; rep++) {
            int flat = rep * 256 + tid;
            int r = flat >> 4, k4 = flat & 15;
            float4 v = *(const float4*)&W[(size_t)r * D + half * 64 + 4 * k4];
            *(float4*)&Ws[r * 68 + 4 * k4] = v;
        }
        __syncthreads();
#pragma unroll
        for (int kk = 0; kk < 64; kk += 4) {
            float4 a[4], wv[4];
#pragma unroll
            for (int i = 0; i < 4; i++) a[i] = *(const float4*)&As[(mg + 8 * i) * 132 + half * 64 + kk];
#pragma unroll
            for (int j = 0; j < 4; j++) wv[j] = *(const float4*)&Ws[(og + 32 * j) * 68 + kk];
#pragma unroll
            for (int i = 0; i < 4; i++)
#pragma unroll
                for (int j = 0; j < 4; j++)
                    acc[i][j] += a[i].x * wv[j].x + a[i].y * wv[j].y + a[i].z * wv[j].z + a[i].w * wv[j].w;
        }
    }
    float bj[4];
#pragma unroll
    for (int j = 0; j < 4; j++) bj[j] = bias[og + 32 * j];
#pragma unroll
    for (int i = 0; i < 4; i++) {
        int row = m0 + mg + 8 * i;
        int orig = inv[row];
        if (orig >= 0) {
#pragma unroll
            for (int j = 0; j < 4; j++)
                out[(size_t)orig * D + og + 32 * j] = acc[i][j] + bj[j];
        }
    }
}

extern "C" void kernel_launch(void* const* d_in, const int* in_sizes, int n_in,
                              void* d_out, int out_size, void* d_ws, size_t ws_size,
                              hipStream_t stream) {
    const float* x         = (const float*)d_in[0];
    const float* edge_attr = (const float*)d_in[1];
    const float* node_W    = (const float*)d_in[2];
    const float* node_b    = (const float*)d_in[3];
    const float* edge_W    = (const float*)d_in[4];
    const float* edge_b    = (const float*)d_in[5];
    const float* emb       = (const float*)d_in[6];
    const float* ln_g      = (const float*)d_in[7];
    const float* ln_b      = (const float*)d_in[8];
    const float* fc_W      = (const float*)d_in[9];
    const float* fc_b      = (const float*)d_in[10];
    const int*   edge_index = (const int*)d_in[11];
    const int*   node_type  = (const int*)d_in[12];
    const int*   edge_type  = (const int*)d_in[13];
    float* out = (float*)d_out;

    char* w = (char*)d_ws;
    auto alloc = [&](size_t bytes) {
        void* p = (void*)w;
        w += (bytes + 255) & ~(size_t)255;
        return p;
    };
    float*  P     = (float*)alloc((size_t)NPAD * D * 4);   // permuted x / layer buffers
    float*  Q     = (float*)alloc((size_t)NPAD * D * 4);
    float*  G     = (float*)alloc((size_t)NPAD * D * 4);   // aggr
    float4* esort = (float4*)alloc((size_t)EE * 32);
    int*    pos   = (int*)alloc((size_t)NN * 4);
    int*    inv   = (int*)alloc((size_t)NPAD * 4);
    int*    deg   = (int*)alloc((size_t)NN * 4);
    int*    offs  = (int*)alloc((size_t)NN * 4);
    int*    cur   = (int*)alloc((size_t)NN * 4);
    int*    bsum  = (int*)alloc(256 * 4);
    int*    boff  = (int*)alloc(256 * 4);
    int*    pc    = (int*)alloc(256 * 4);
    int*    po    = (int*)alloc(256 * 4);
    int*    meta  = (int*)alloc(8 * 4);

    hipMemsetAsync(deg, 0, (size_t)NN * 4, stream);
    hipMemsetAsync(inv, 0xFF, (size_t)NPAD * 4, stream);   // -1 = "gap row", k_fc skips

    k_pcount<<<NB, 256, 0, stream>>>(node_type, pc);
    k_pscan<<<1, 256, 0, stream>>>(pc, po, meta);
    k_passign<<<NB, 256, 0, stream>>>(node_type, po, meta, pos, inv);
    k_permx<<<(NN * 32 + 255) / 256, 256, 0, stream>>>(x, pos, P);

    k_hist<<<(EE + 255) / 256, 256, 0, stream>>>(edge_index + EE, deg);
    k_scan_bsum<<<NB, 256, 0, stream>>>(deg, bsum);
    k_scan_boff<<<1, 256, 0, stream>>>(bsum, boff);
    k_scan_offs<<<NB, 256, 0, stream>>>(deg, boff, offs, cur);
    k_edge<<<(EE + 255) / 256, 256, 0, stream>>>(edge_attr, edge_W, edge_b, emb,
                                                 edge_index, edge_type, pos, cur, esort);

    // layer rotation: P -> Q -> P -> Q   (in, out per layer)
    const float* hin = P;
    float* outs[LL] = {Q, P, Q};
    for (int l = 0; l < LL; l++) {
        k_gather<<<NN / 2, 256, 0, stream>>>(hin, offs, deg, pos, esort, l, G);
        k_node<<<NTILE, 256, 0, stream>>>(G, hin,
                                          node_W + (size_t)l * NT * D * D,
                                          node_b + (size_t)l * NT * D,
                                          ln_g + (size_t)l * D,
                                          ln_b + (size_t)l * D,
                                          meta, outs[l]);
        hin = outs[l];
    }
    k_fc<<<NTILE, 256, 0, stream>>>(hin, fc_W, fc_b, inv, out);
}